// Round 3
// baseline (6179.011 us; speedup 1.0000x reference)
//
#include <hip/hip_runtime.h>
#include <hip/hip_bf16.h>

#define BB 32
#define HH 56
#define WW 56
#define CC 384
#define HEADS 12
#define WSZ 7
#define SHIFT 3
#define HD 32
#define NN 49
#define SCALE 0.17677669529663687f  // 1/sqrt(32)

#define NWIN_TOT 2048            // B * 64 windows
#define ROWS_TOT (BB * HH * WW)  // 100352

// ---------------------------------------------------------------------------
// K1: LN1 + cyclic shift(-3,-3) + window partition.  One wave per output row.
// ---------------------------------------------------------------------------
__global__ __launch_bounds__(64) void ln_part_k(const float* __restrict__ x,
                                                const float* __restrict__ g,
                                                const float* __restrict__ bta,
                                                float* __restrict__ out, int win_off) {
    int r = blockIdx.x;          // chunk-local windowed row
    int lane = threadIdx.x;      // 0..63
    int wl = r / NN, n = r % NN;
    int wg = win_off + wl;       // global window id
    int bi = wg >> 6;            // image
    int w_ = wg & 63;
    int wh = w_ >> 3, wwi = w_ & 7;
    int i = n / WSZ, j = n % WSZ;
    int ho = (wh * WSZ + i + SHIFT) % HH;
    int wo = (wwi * WSZ + j + SHIFT) % WW;
    const float* src = x + ((size_t)bi * (HH * WW) + ho * WW + wo) * CC;

    float xv[6];
    float s = 0.f, s2 = 0.f;
#pragma unroll
    for (int k = 0; k < 6; k++) {
        float v = src[lane + k * 64];
        xv[k] = v; s += v; s2 += v * v;
    }
#pragma unroll
    for (int off = 32; off > 0; off >>= 1) {
        s += __shfl_down(s, off);
        s2 += __shfl_down(s2, off);
    }
    s = __shfl(s, 0); s2 = __shfl(s2, 0);
    float mean = s * (1.0f / CC);
    float var = s2 * (1.0f / CC) - mean * mean;
    float rstd = rsqrtf(var + 1e-5f);

    float* dst = out + (size_t)r * CC;
#pragma unroll
    for (int k = 0; k < 6; k++) {
        int c = lane + k * 64;
        dst[c] = (xv[k] - mean) * rstd * g[c] + bta[c];
    }
}

// ---------------------------------------------------------------------------
// K4: LN2 on residual stream (identity row mapping)
// ---------------------------------------------------------------------------
__global__ __launch_bounds__(64) void ln2_k(const float* __restrict__ xin,
                                            const float* __restrict__ g,
                                            const float* __restrict__ bta,
                                            float* __restrict__ out, int row_off) {
    int r = blockIdx.x;
    int lane = threadIdx.x;
    const float* src = xin + (size_t)(row_off + r) * CC;
    float xv[6];
    float s = 0.f, s2 = 0.f;
#pragma unroll
    for (int k = 0; k < 6; k++) {
        float v = src[lane + k * 64];
        xv[k] = v; s += v; s2 += v * v;
    }
#pragma unroll
    for (int off = 32; off > 0; off >>= 1) {
        s += __shfl_down(s, off);
        s2 += __shfl_down(s2, off);
    }
    s = __shfl(s, 0); s2 = __shfl(s2, 0);
    float mean = s * (1.0f / CC);
    float var = s2 * (1.0f / CC) - mean * mean;
    float rstd = rsqrtf(var + 1e-5f);
    float* dst = out + (size_t)r * CC;
#pragma unroll
    for (int k = 0; k < 6; k++) {
        int c = lane + k * 64;
        dst[c] = (xv[k] - mean) * rstd * g[c] + bta[c];
    }
}

// ---------------------------------------------------------------------------
// K2: generic GEMM  out = A(MxK) @ W(KxN) + bias, templated epilogue.
// 64x64 tile / block (256 thr, 4x4 per thread), BK=16, f32 accumulate.
// EPI 0: store         EPI 1: exact GELU then store
// EPI 2: proj scatter (window reverse + unshift) + residual add -> dout
// EPI 3: dout[row] += v (final residual)
// ---------------------------------------------------------------------------
template <int EPI>
__global__ __launch_bounds__(256) void gemm_k(const float* __restrict__ A,
                                              const float* __restrict__ Wm,
                                              const float* __restrict__ bias,
                                              float* __restrict__ out,
                                              int M, int Nn, int K,
                                              const float* __restrict__ resid,
                                              float* __restrict__ dout, int off_idx) {
    __shared__ float As[16][64];
    __shared__ float Bs[16][64];
    int tid = threadIdx.x;
    int row0 = blockIdx.y * 64, col0 = blockIdx.x * 64;
    int ty = tid >> 4, tx = tid & 15;
    int aRow = tid >> 2;           // 0..63
    int aK = (tid & 3) * 4;        // 0,4,8,12
    int bRow = tid >> 4;           // 0..15
    int bCol = (tid & 15) * 4;     // 0..60

    float acc[4][4] = {};
    const float* Aptr = A + (size_t)(row0 + aRow) * K + aK;
    const float* Bptr = Wm + (size_t)bRow * Nn + col0 + bCol;

    for (int kt = 0; kt < K; kt += 16) {
        float4 av = *reinterpret_cast<const float4*>(Aptr + kt);
        float4 bv = *reinterpret_cast<const float4*>(Bptr + (size_t)kt * Nn);
        As[aK + 0][aRow] = av.x;
        As[aK + 1][aRow] = av.y;
        As[aK + 2][aRow] = av.z;
        As[aK + 3][aRow] = av.w;
        *reinterpret_cast<float4*>(&Bs[bRow][bCol]) = bv;
        __syncthreads();
#pragma unroll
        for (int kk = 0; kk < 16; kk++) {
            float4 a = *reinterpret_cast<const float4*>(&As[kk][ty * 4]);
            float4 b = *reinterpret_cast<const float4*>(&Bs[kk][tx * 4]);
            float ar[4] = {a.x, a.y, a.z, a.w};
            float br[4] = {b.x, b.y, b.z, b.w};
#pragma unroll
            for (int i = 0; i < 4; i++)
#pragma unroll
                for (int j = 0; j < 4; j++) acc[i][j] += ar[i] * br[j];
        }
        __syncthreads();
    }

#pragma unroll
    for (int i = 0; i < 4; i++) {
        int r = row0 + ty * 4 + i;
#pragma unroll
        for (int j = 0; j < 4; j++) {
            int c = col0 + tx * 4 + j;
            float v = acc[i][j] + bias[c];
            if constexpr (EPI == 0) {
                out[(size_t)r * Nn + c] = v;
            } else if constexpr (EPI == 1) {
                v = 0.5f * v * (1.0f + erff(v * 0.70710678118f));
                out[(size_t)r * Nn + c] = v;
            } else if constexpr (EPI == 2) {
                int wl = r / NN, n = r % NN;
                int wg = off_idx + wl;
                int bi = wg >> 6, w_ = wg & 63;
                int wh = w_ >> 3, wwi = w_ & 7;
                int i1 = n / WSZ, j1 = n % WSZ;
                int ho = (wh * WSZ + i1 + SHIFT) % HH;
                int wo = (wwi * WSZ + j1 + SHIFT) % WW;
                size_t gidx = ((size_t)bi * (HH * WW) + ho * WW + wo) * CC + c;
                dout[gidx] = resid[gidx] + v;
            } else {  // EPI == 3
                size_t gidx = (size_t)(off_idx + r) * CC + c;
                dout[gidx] = dout[gidx] + v;
            }
        }
    }
}

// ---------------------------------------------------------------------------
// K3: attention for one (window, head).  LDS resident.
// ---------------------------------------------------------------------------
__global__ __launch_bounds__(256) void attn_k(const float* __restrict__ qkv,
                                              const float* __restrict__ rpb,
                                              float* __restrict__ xa, int win_off) {
    __shared__ float qs[NN * HD];
    __shared__ float ks[NN * HD];
    __shared__ float vs[NN * HD];
    __shared__ float Sm[NN * NN];
    int tid = threadIdx.x;
    int h = blockIdx.x % HEADS;
    int wl = blockIdx.x / HEADS;
    int wg = win_off + wl;

    const float* base = qkv + (size_t)wl * NN * (3 * CC);
    for (int t = tid; t < NN * HD; t += 256) {
        int n = t >> 5, d = t & 31;
        const float* rowp = base + (size_t)n * (3 * CC) + h * HD + d;
        qs[t] = rowp[0] * SCALE;
        ks[t] = rowp[CC];
        vs[t] = rowp[2 * CC];
    }
    __syncthreads();

    int w_ = wg & 63, wh = w_ >> 3, wwc = w_ & 7;
    for (int e = tid; e < NN * NN; e += 256) {
        int n = e / NN, m = e % NN;
        const float* qp = qs + n * HD;
        const float* kp = ks + m * HD;
        float acc = 0.f;
#pragma unroll
        for (int d = 0; d < HD; d++) acc += qp[d] * kp[d];
        int i1 = n / WSZ, j1 = n % WSZ, i2 = m / WSZ, j2 = m % WSZ;
        int ridx = (i1 - i2 + WSZ - 1) * (2 * WSZ - 1) + (j1 - j2 + WSZ - 1);
        acc += rpb[ridx * HEADS + h];
        int rh1 = (wh < 7) ? 0 : ((i1 < 4) ? 1 : 2);
        int rh2 = (wh < 7) ? 0 : ((i2 < 4) ? 1 : 2);
        int rw1 = (wwc < 7) ? 0 : ((j1 < 4) ? 1 : 2);
        int rw2 = (wwc < 7) ? 0 : ((j2 < 4) ? 1 : 2);
        if (rh1 != rh2 || rw1 != rw2) acc -= 100.0f;
        Sm[e] = acc;
    }
    __syncthreads();

    if (tid < NN) {
        float* row = Sm + tid * NN;
        float mx = -1e30f;
        for (int m = 0; m < NN; m++) mx = fmaxf(mx, row[m]);
        float sum = 0.f;
        for (int m = 0; m < NN; m++) {
            float ev = __expf(row[m] - mx);
            row[m] = ev; sum += ev;
        }
        float inv = 1.0f / sum;
        for (int m = 0; m < NN; m++) row[m] *= inv;
    }
    __syncthreads();

    for (int o = tid; o < NN * HD; o += 256) {
        int n = o >> 5, d = o & 31;
        const float* pr = Sm + n * NN;
        float acc = 0.f;
        for (int m = 0; m < NN; m++) acc += pr[m] * vs[m * HD + d];
        xa[((size_t)wl * NN + n) * CC + h * HD + d] = acc;
    }
}

// ---------------------------------------------------------------------------
extern "C" void kernel_launch(void* const* d_in, const int* in_sizes, int n_in,
                              void* d_out, int out_size, void* d_ws, size_t ws_size,
                              hipStream_t stream) {
    const float* x     = (const float*)d_in[0];
    const float* ln1g  = (const float*)d_in[1];
    const float* ln1b  = (const float*)d_in[2];
    const float* qkvw  = (const float*)d_in[3];
    const float* qkvb  = (const float*)d_in[4];
    const float* rpb   = (const float*)d_in[5];
    const float* projw = (const float*)d_in[6];
    const float* projb = (const float*)d_in[7];
    const float* ln2g  = (const float*)d_in[8];
    const float* ln2b  = (const float*)d_in[9];
    const float* fc1w  = (const float*)d_in[10];
    const float* fc1b  = (const float*)d_in[11];
    const float* fc2w  = (const float*)d_in[12];
    const float* fc2b  = (const float*)d_in[13];
    float* out = (float*)d_out;
    char* ws = (char*)d_ws;

    // ---- adaptive attention chunking (f32 sizes): bufA (xa/ln) + bufB (qkv) ----
    int nca = 4;
    size_t offB_a = 0;
    for (; nca <= 32; nca *= 2) {
        int Wc = NWIN_TOT / nca;
        size_t a = (size_t)Wc * NN * CC * 4;           // bufA bytes
        a = (a + 1023) & ~(size_t)1023;
        size_t b = (size_t)Wc * NN * (3 * CC) * 4;     // qkv bytes
        if (a + b <= ws_size) { offB_a = a; break; }
    }
    if (nca > 32) { nca = 32; offB_a = (((size_t)(NWIN_TOT / 32) * NN * CC * 4) + 1023) & ~(size_t)1023; }
    int Wc = NWIN_TOT / nca;
    int Rw = Wc * NN;  // rows per attn chunk (multiple of 64 for nca<=32)

    for (int c = 0; c < nca; c++) {
        int woff = c * Wc;
        float* bufA = (float*)ws;
        float* bufB = (float*)(ws + offB_a);
        ln_part_k<<<dim3(Rw), dim3(64), 0, stream>>>(x, ln1g, ln1b, bufA, woff);
        gemm_k<0><<<dim3(1152 / 64, Rw / 64), dim3(256), 0, stream>>>(
            bufA, qkvw, qkvb, bufB, Rw, 1152, 384, nullptr, nullptr, 0);
        attn_k<<<dim3(Wc * HEADS), dim3(256), 0, stream>>>(bufB, rpb, bufA, woff);
        gemm_k<2><<<dim3(384 / 64, Rw / 64), dim3(256), 0, stream>>>(
            bufA, projw, projb, nullptr, Rw, 384, 384, x, out, woff);
    }

    // ---- adaptive MLP chunking (f32): ln2-out (Rc x 384) + m1 (Rc x 1536) ----
    int ncm = 8;
    size_t offB_m = 0;
    for (; ncm <= 32; ncm *= 2) {
        int Rc = ROWS_TOT / ncm;
        size_t a = (size_t)Rc * CC * 4;
        a = (a + 1023) & ~(size_t)1023;
        size_t b = (size_t)Rc * (4 * CC) * 4;
        if (a + b <= ws_size) { offB_m = a; break; }
    }
    if (ncm > 32) { ncm = 32; offB_m = (((size_t)(ROWS_TOT / 32) * CC * 4) + 1023) & ~(size_t)1023; }
    int Rc = ROWS_TOT / ncm;

    for (int c = 0; c < ncm; c++) {
        int roff = c * Rc;
        float* bufA = (float*)ws;
        float* bufB = (float*)(ws + offB_m);
        ln2_k<<<dim3(Rc), dim3(64), 0, stream>>>(out, ln2g, ln2b, bufA, roff);
        gemm_k<1><<<dim3(1536 / 64, Rc / 64), dim3(256), 0, stream>>>(
            bufA, fc1w, fc1b, bufB, Rc, 1536, 384, nullptr, nullptr, 0);
        gemm_k<3><<<dim3(384 / 64, Rc / 64), dim3(256), 0, stream>>>(
            bufB, fc2w, fc2b, nullptr, Rc, 384, 1536, nullptr, out, roff);
    }
}

// Round 4
// 2137.692 us; speedup vs baseline: 2.8905x; 2.8905x over previous
//
#include <hip/hip_runtime.h>
#include <hip/hip_bf16.h>

typedef unsigned short u16;
typedef unsigned long long u64;

#define BB 32
#define HH 56
#define WW 56
#define CC 384
#define HEADS 12
#define WSZ 7
#define SHIFT 3
#define HD 32
#define NN 49
#define SCALE 0.17677669529663687f  // 1/sqrt(32)

#define NWIN_TOT 2048            // B * 64 windows
#define ROWS_TOT (BB * HH * WW)  // 100352

typedef __attribute__((ext_vector_type(8))) __bf16 v8bf;
typedef __attribute__((ext_vector_type(4))) float v4f;

__device__ __forceinline__ u16 f2bu(float f) {
    unsigned u = __float_as_uint(f);
    unsigned r = (u + 0x7fffu + ((u >> 16) & 1u)) >> 16;
    return (u16)r;
}
__device__ __forceinline__ float bu2f(u16 h) { return __uint_as_float(((unsigned)h) << 16); }

// ---------------------------------------------------------------------------
// Weight convert + transpose: in f32 (K x N) -> out bf16 (N x K)
// ---------------------------------------------------------------------------
__global__ __launch_bounds__(256) void cvtT_k(const float* __restrict__ in,
                                              u16* __restrict__ outb, int K, int N) {
    __shared__ float sh[32][33];
    int tx = threadIdx.x & 31, ty = threadIdx.x >> 5;  // 32 x 8
    int n0 = blockIdx.x * 32, k0 = blockIdx.y * 32;
#pragma unroll
    for (int r = 0; r < 4; r++) {
        int k = k0 + ty + 8 * r;
        sh[ty + 8 * r][tx] = in[(size_t)k * N + n0 + tx];
    }
    __syncthreads();
#pragma unroll
    for (int r = 0; r < 4; r++) {
        int n = n0 + ty + 8 * r;
        outb[(size_t)n * K + k0 + tx] = f2bu(sh[tx][ty + 8 * r]);
    }
}

// ---------------------------------------------------------------------------
// K1: LN1 + cyclic shift(-3,-3) + window partition -> bf16 rows
// ---------------------------------------------------------------------------
__global__ __launch_bounds__(64) void ln_part_k(const float* __restrict__ x,
                                                const float* __restrict__ g,
                                                const float* __restrict__ bta,
                                                u16* __restrict__ out, int win_off) {
    int r = blockIdx.x;
    int lane = threadIdx.x;
    int wl = r / NN, n = r % NN;
    int wg = win_off + wl;
    int bi = wg >> 6;
    int w_ = wg & 63;
    int wh = w_ >> 3, wwi = w_ & 7;
    int i = n / WSZ, j = n % WSZ;
    int ho = (wh * WSZ + i + SHIFT) % HH;
    int wo = (wwi * WSZ + j + SHIFT) % WW;
    const float* src = x + ((size_t)bi * (HH * WW) + ho * WW + wo) * CC;

    float xv[6];
    float s = 0.f, s2 = 0.f;
#pragma unroll
    for (int k = 0; k < 6; k++) {
        float v = src[lane + k * 64];
        xv[k] = v; s += v; s2 += v * v;
    }
#pragma unroll
    for (int off = 32; off > 0; off >>= 1) {
        s += __shfl_down(s, off);
        s2 += __shfl_down(s2, off);
    }
    s = __shfl(s, 0); s2 = __shfl(s2, 0);
    float mean = s * (1.0f / CC);
    float var = s2 * (1.0f / CC) - mean * mean;
    float rstd = rsqrtf(var + 1e-5f);

    u16* dst = out + (size_t)r * CC;
#pragma unroll
    for (int k = 0; k < 6; k++) {
        int c = lane + k * 64;
        dst[c] = f2bu((xv[k] - mean) * rstd * g[c] + bta[c]);
    }
}

// ---------------------------------------------------------------------------
// K4: LN2 on residual stream -> bf16 rows
// ---------------------------------------------------------------------------
__global__ __launch_bounds__(64) void ln2_k(const float* __restrict__ xin,
                                            const float* __restrict__ g,
                                            const float* __restrict__ bta,
                                            u16* __restrict__ out, int row_off) {
    int r = blockIdx.x;
    int lane = threadIdx.x;
    const float* src = xin + (size_t)(row_off + r) * CC;
    float xv[6];
    float s = 0.f, s2 = 0.f;
#pragma unroll
    for (int k = 0; k < 6; k++) {
        float v = src[lane + k * 64];
        xv[k] = v; s += v; s2 += v * v;
    }
#pragma unroll
    for (int off = 32; off > 0; off >>= 1) {
        s += __shfl_down(s, off);
        s2 += __shfl_down(s2, off);
    }
    s = __shfl(s, 0); s2 = __shfl(s2, 0);
    float mean = s * (1.0f / CC);
    float var = s2 * (1.0f / CC) - mean * mean;
    float rstd = rsqrtf(var + 1e-5f);
    u16* dst = out + (size_t)r * CC;
#pragma unroll
    for (int k = 0; k < 6; k++) {
        int c = lane + k * 64;
        dst[c] = f2bu((xv[k] - mean) * rstd * g[c] + bta[c]);
    }
}

// ---------------------------------------------------------------------------
// K2: MFMA GEMM  C = A(MxK bf16) @ W^T(NxK bf16) + bias(f32)
// 128x128 tile, BK=32, 256 thr = 4 waves, wave = 64x64 via 4x4 mfma 16x16x32.
// EPI 0: store bf16   EPI 1: exact GELU -> bf16
// EPI 2: proj scatter (window reverse + unshift) + residual -> f32 dout
// EPI 3: dout += v (final residual, f32)
// ---------------------------------------------------------------------------
#define LDK 40  // 32 + 8 pad (bf16 units); row stride 80B

template <int EPI>
__global__ __launch_bounds__(256) void mgemm_k(const u16* __restrict__ A,
                                               const u16* __restrict__ Bt,
                                               const float* __restrict__ bias,
                                               u16* __restrict__ outb,
                                               int M, int Nn, int K,
                                               const float* __restrict__ resid,
                                               float* __restrict__ dout, int off_idx) {
    __shared__ u16 As[128 * LDK];
    __shared__ u16 Bs[128 * LDK];
    int tid = threadIdx.x;
    int lane = tid & 63, wave = tid >> 6;
    int wy = (wave >> 1) * 64, wx = (wave & 1) * 64;
    int row0 = blockIdx.y * 128, col0 = blockIdx.x * 128;
    int mrow = lane & 15, kq = lane >> 4;

    v4f acc[4][4];
    v4f zz = {0.f, 0.f, 0.f, 0.f};
#pragma unroll
    for (int i = 0; i < 4; i++)
#pragma unroll
        for (int j = 0; j < 4; j++) acc[i][j] = zz;

    int m0 = tid >> 3;            // 0..31 (+32*r)
    int ksl = (tid & 7) * 4;      // 0,4,...,28
    const u16* Ab = A + (size_t)row0 * K;
    const u16* Bb = Bt + (size_t)col0 * K;

    for (int kt = 0; kt < K; kt += 32) {
#pragma unroll
        for (int r = 0; r < 4; r++) {
            int m = m0 + 32 * r;
            u64 av = *(const u64*)(Ab + (size_t)m * K + kt + ksl);
            u64 bv = *(const u64*)(Bb + (size_t)m * K + kt + ksl);
            *(u64*)(&As[m * LDK + ksl]) = av;
            *(u64*)(&Bs[m * LDK + ksl]) = bv;
        }
        __syncthreads();
        v8bf af[4], bfr[4];
#pragma unroll
        for (int i = 0; i < 4; i++) {
            af[i]  = *(const v8bf*)(&As[(wy + i * 16 + mrow) * LDK + 8 * kq]);
            bfr[i] = *(const v8bf*)(&Bs[(wx + i * 16 + mrow) * LDK + 8 * kq]);
        }
#pragma unroll
        for (int i = 0; i < 4; i++)
#pragma unroll
            for (int j = 0; j < 4; j++)
                acc[i][j] = __builtin_amdgcn_mfma_f32_16x16x32_bf16(af[i], bfr[j], acc[i][j], 0, 0, 0);
        __syncthreads();
    }

#pragma unroll
    for (int i = 0; i < 4; i++) {
#pragma unroll
        for (int j = 0; j < 4; j++) {
#pragma unroll
            for (int r = 0; r < 4; r++) {
                int row = row0 + wy + i * 16 + kq * 4 + r;
                int col = col0 + wx + j * 16 + mrow;
                float v = acc[i][j][r] + bias[col];
                if constexpr (EPI == 0) {
                    outb[(size_t)row * Nn + col] = f2bu(v);
                } else if constexpr (EPI == 1) {
                    v = 0.5f * v * (1.0f + erff(v * 0.70710678118f));
                    outb[(size_t)row * Nn + col] = f2bu(v);
                } else if constexpr (EPI == 2) {
                    int wl = row / NN, n = row % NN;
                    int wg = off_idx + wl;
                    int bi = wg >> 6, w_ = wg & 63;
                    int wh = w_ >> 3, wwi = w_ & 7;
                    int i1 = n / WSZ, j1 = n % WSZ;
                    int ho = (wh * WSZ + i1 + SHIFT) % HH;
                    int wo = (wwi * WSZ + j1 + SHIFT) % WW;
                    size_t gidx = ((size_t)bi * (HH * WW) + ho * WW + wo) * CC + col;
                    dout[gidx] = resid[gidx] + v;
                } else {  // EPI 3
                    size_t gidx = (size_t)(off_idx + row) * CC + col;
                    dout[gidx] = dout[gidx] + v;
                }
            }
        }
    }
}

// ---------------------------------------------------------------------------
// K3: attention for one (window, head). bf16 in/out, f32 LDS compute.
// ---------------------------------------------------------------------------
__global__ __launch_bounds__(256) void attn_k(const u16* __restrict__ qkv,
                                              const float* __restrict__ rpb,
                                              u16* __restrict__ xa, int win_off) {
    __shared__ float qs[NN * HD];
    __shared__ float ks[NN * HD];
    __shared__ float vs[NN * HD];
    __shared__ float Sm[NN * NN];
    int tid = threadIdx.x;
    int h = blockIdx.x % HEADS;
    int wl = blockIdx.x / HEADS;
    int wg = win_off + wl;

    const u16* base = qkv + (size_t)wl * NN * (3 * CC);
    for (int t = tid; t < NN * HD; t += 256) {
        int n = t >> 5, d = t & 31;
        const u16* rowp = base + (size_t)n * (3 * CC) + h * HD + d;
        qs[t] = bu2f(rowp[0]) * SCALE;
        ks[t] = bu2f(rowp[CC]);
        vs[t] = bu2f(rowp[2 * CC]);
    }
    __syncthreads();

    int w_ = wg & 63, wh = w_ >> 3, wwc = w_ & 7;
    for (int e = tid; e < NN * NN; e += 256) {
        int n = e / NN, m = e % NN;
        const float* qp = qs + n * HD;
        const float* kp = ks + m * HD;
        float acc = 0.f;
#pragma unroll
        for (int d = 0; d < HD; d++) acc += qp[d] * kp[d];
        int i1 = n / WSZ, j1 = n % WSZ, i2 = m / WSZ, j2 = m % WSZ;
        int ridx = (i1 - i2 + WSZ - 1) * (2 * WSZ - 1) + (j1 - j2 + WSZ - 1);
        acc += rpb[ridx * HEADS + h];
        int rh1 = (wh < 7) ? 0 : ((i1 < 4) ? 1 : 2);
        int rh2 = (wh < 7) ? 0 : ((i2 < 4) ? 1 : 2);
        int rw1 = (wwc < 7) ? 0 : ((j1 < 4) ? 1 : 2);
        int rw2 = (wwc < 7) ? 0 : ((j2 < 4) ? 1 : 2);
        if (rh1 != rh2 || rw1 != rw2) acc -= 100.0f;
        Sm[e] = acc;
    }
    __syncthreads();

    if (tid < NN) {
        float* row = Sm + tid * NN;
        float mx = -1e30f;
        for (int m = 0; m < NN; m++) mx = fmaxf(mx, row[m]);
        float sum = 0.f;
        for (int m = 0; m < NN; m++) {
            float ev = __expf(row[m] - mx);
            row[m] = ev; sum += ev;
        }
        float inv = 1.0f / sum;
        for (int m = 0; m < NN; m++) row[m] *= inv;
    }
    __syncthreads();

    for (int o = tid; o < NN * HD; o += 256) {
        int n = o >> 5, d = o & 31;
        const float* pr = Sm + n * NN;
        float acc = 0.f;
        for (int m = 0; m < NN; m++) acc += pr[m] * vs[m * HD + d];
        xa[((size_t)wl * NN + n) * CC + h * HD + d] = f2bu(acc);
    }
}

// ---------------------------------------------------------------------------
extern "C" void kernel_launch(void* const* d_in, const int* in_sizes, int n_in,
                              void* d_out, int out_size, void* d_ws, size_t ws_size,
                              hipStream_t stream) {
    const float* x     = (const float*)d_in[0];
    const float* ln1g  = (const float*)d_in[1];
    const float* ln1b  = (const float*)d_in[2];
    const float* qkvw  = (const float*)d_in[3];
    const float* qkvb  = (const float*)d_in[4];
    const float* rpb   = (const float*)d_in[5];
    const float* projw = (const float*)d_in[6];
    const float* projb = (const float*)d_in[7];
    const float* ln2g  = (const float*)d_in[8];
    const float* ln2b  = (const float*)d_in[9];
    const float* fc1w  = (const float*)d_in[10];
    const float* fc1b  = (const float*)d_in[11];
    const float* fc2w  = (const float*)d_in[12];
    const float* fc2b  = (const float*)d_in[13];
    float* out = (float*)d_out;
    char* ws = (char*)d_ws;

    // ---- weight regions (bf16, transposed to NxK) ----
    size_t o = 0;
    auto walloc = [&](size_t elems) { size_t c = o; o += ((elems * 2 + 1023) & ~(size_t)1023); return c; };
    size_t o_qkvT = walloc((size_t)1152 * 384);
    size_t o_projT = walloc((size_t)384 * 384);
    size_t o_fc1T = walloc((size_t)1536 * 384);
    size_t o_fc2T = walloc((size_t)384 * 1536);
    size_t wgt_end = (o + 1023) & ~(size_t)1023;
    u16* qkvT = (u16*)(ws + o_qkvT);
    u16* projT = (u16*)(ws + o_projT);
    u16* fc1T = (u16*)(ws + o_fc1T);
    u16* fc2T = (u16*)(ws + o_fc2T);

    cvtT_k<<<dim3(1152 / 32, 384 / 32), dim3(256), 0, stream>>>(qkvw, qkvT, 384, 1152);
    cvtT_k<<<dim3(384 / 32, 384 / 32), dim3(256), 0, stream>>>(projw, projT, 384, 384);
    cvtT_k<<<dim3(1536 / 32, 384 / 32), dim3(256), 0, stream>>>(fc1w, fc1T, 384, 1536);
    cvtT_k<<<dim3(384 / 32, 1536 / 32), dim3(256), 0, stream>>>(fc2w, fc2T, 1536, 384);

    size_t avail = (ws_size > wgt_end) ? ws_size - wgt_end : 0;

    // ---- adaptive attention chunking (bf16 bufs): bufA (ln/xa) + bufB (qkv) ----
    int nca = 4;
    size_t offB_a = 0;
    for (; nca <= 16; nca *= 2) {
        int Wc = NWIN_TOT / nca;
        size_t a = (size_t)Wc * NN * CC * 2;
        a = (a + 1023) & ~(size_t)1023;
        size_t b = (size_t)Wc * NN * (3 * CC) * 2;
        if (a + b <= avail) { offB_a = a; break; }
    }
    if (nca > 16) { nca = 16; offB_a = (((size_t)(NWIN_TOT / 16) * NN * CC * 2) + 1023) & ~(size_t)1023; }
    int Wc = NWIN_TOT / nca;
    int Rw = Wc * NN;  // multiple of 128 for nca in {4,8,16}

    for (int c = 0; c < nca; c++) {
        int woff = c * Wc;
        u16* bufA = (u16*)(ws + wgt_end);
        u16* bufB = (u16*)(ws + wgt_end + offB_a);
        ln_part_k<<<dim3(Rw), dim3(64), 0, stream>>>(x, ln1g, ln1b, bufA, woff);
        mgemm_k<0><<<dim3(1152 / 128, Rw / 128), dim3(256), 0, stream>>>(
            bufA, qkvT, qkvb, bufB, Rw, 1152, 384, nullptr, nullptr, 0);
        attn_k<<<dim3(Wc * HEADS), dim3(256), 0, stream>>>(bufB, rpb, bufA, woff);
        mgemm_k<2><<<dim3(384 / 128, Rw / 128), dim3(256), 0, stream>>>(
            bufA, projT, projb, nullptr, Rw, 384, 384, x, out, woff);
    }

    // ---- adaptive MLP chunking: ln2-out (Rc x 384 bf16) + m1 (Rc x 1536 bf16) ----
    int ncm = 8;
    size_t offB_m = 0;
    for (; ncm <= 16; ncm *= 2) {
        int Rc = ROWS_TOT / ncm;
        size_t a = (size_t)Rc * CC * 2;
        a = (a + 1023) & ~(size_t)1023;
        size_t b = (size_t)Rc * (4 * CC) * 2;
        if (a + b <= avail) { offB_m = a; break; }
    }
    if (ncm > 16) { ncm = 16; offB_m = (((size_t)(ROWS_TOT / 16) * CC * 2) + 1023) & ~(size_t)1023; }
    int Rc = ROWS_TOT / ncm;

    for (int c = 0; c < ncm; c++) {
        int roff = c * Rc;
        u16* bufA = (u16*)(ws + wgt_end);
        u16* bufB = (u16*)(ws + wgt_end + offB_m);
        ln2_k<<<dim3(Rc), dim3(64), 0, stream>>>(out, ln2g, ln2b, bufA, roff);
        mgemm_k<1><<<dim3(1536 / 128, Rc / 128), dim3(256), 0, stream>>>(
            bufA, fc1T, fc1b, bufB, Rc, 1536, 384, nullptr, nullptr, 0);
        mgemm_k<3><<<dim3(384 / 128, Rc / 128), dim3(256), 0, stream>>>(
            bufB, fc2T, fc2b, nullptr, Rc, 384, 1536, nullptr, out, roff);
    }
}